// Round 12
// baseline (13.398 us; speedup 1.0000x reference)
//
#include <hip/hip_runtime.h>

#define NB    64
#define NPT   8192
#define GSZ   128
#define TPB   1024
#define BPB   4                       // blocks per batch
#define NBLK  (NB * BPB)              // 256 = 1 block/CU, full chip
#define ROWS  32                      // output stripe rows per block

typedef float vf4 __attribute__((ext_vector_type(4)));

// Per-point permutohedral math. Bitwise-replicates XLA-CPU f32 (verified
// absmax == 0.0 rounds 1-11): pc = v*190.0f; elevated = E @ pc (FMA chain);
// u = rint(ev/3) via Markstein constant-division (bit-identical to IEEE /3,
// verified on HW in R11); round-half-even; exact integer fixup.
__device__ __forceinline__ void compute_pt(float v0, float v1, float v2,
                                           int& u0o, int& u1o) {
    const float s6 = (float)2.449489742783178098197284074705891391989;
    const float ca = 2.0f / s6;
    const float cb = -1.0f / s6;
    const float y3 = 0.333333343267440796f;   // 0x3EAAAAAB = RN(1/3)
    float p0 = v0 * 190.0f;
    float p1 = v1 * 190.0f;
    float p2 = v2 * 190.0f;
    float ev0 = __builtin_fmaf(cb, p2, __builtin_fmaf(cb, p1, ca * p0));
    float ev1 = __builtin_fmaf(cb, p2, __builtin_fmaf(ca, p1, cb * p0));
    float ev2 = __builtin_fmaf(ca, p2, __builtin_fmaf(cb, p1, cb * p0));
    float t0 = ev0 * y3, t1 = ev1 * y3, t2 = ev2 * y3;
    float q0 = __builtin_fmaf(__builtin_fmaf(-3.0f, t0, ev0), y3, t0);
    float q1 = __builtin_fmaf(__builtin_fmaf(-3.0f, t1, ev1), y3, t1);
    float q2 = __builtin_fmaf(__builtin_fmaf(-3.0f, t2, ev2), y3, t2);
    float rg0 = rintf(q0), rg1 = rintf(q1), rg2 = rintf(q2);  // half-even
    int u0 = (int)rg0, u1 = (int)rg1, u2 = (int)rg2;
    float e0 = ev0 - rg0 * 3.0f;   // exact (moderate range)
    float e1 = ev1 - rg1 * 3.0f;
    float e2 = ev2 - rg2 * 3.0f;
    int rk0 = (int)(e1 > e0) + (int)(e2 > e0);
    int rk1 = (int)(e0 >= e1) + (int)(e2 > e1);   // (>)+(==) folded
    int rs = u0 + u1 + u2;
    if (rs > 0) {
        if (rk0 >= 3 - rs) u0 -= 1;
        if (rk1 >= 3 - rs) u1 -= 1;
    } else if (rs < 0) {
        if (rk0 < -rs) u0 += 1;
        if (rk1 < -rs) u1 += 1;
    }
    u0o = u0; u1o = u1;
}

// One block per (batch, 32-row output stripe). NT-zero own stripe FIRST
// (write drains under the scan), scan ALL batch points (exact local
// batch-min, zero inter-block deps), then scatter the ~3 survivors via
// global atomics. No LDS tile, no fences, no ws. Stripe is block-owned;
// __syncthreads' vmcnt(0) drain orders zeros before atomics.
__global__ __launch_bounds__(TPB, 4) void kone(const float* __restrict__ x,
                                               float* __restrict__ out) {
    const int wg = blockIdx.x;
    const int bid = ((wg & 7) << 5) | (wg >> 3);  // XCD co-location swizzle (perf only)
    const int b = bid >> 2, r = bid & 3;
    const int t = threadIdx.x;
    const int rlo = r * ROWS;

    // 1) NT-zero own stripe (3 float4 stores; drain overlaps the scan)
    float* ob = out + (size_t)b * 3 * GSZ * GSZ + rlo * GSZ;
    const vf4 z4 = {0.f, 0.f, 0.f, 0.f};
#pragma unroll
    for (int c = 0; c < 3; ++c)
        __builtin_nontemporal_store(z4, &((vf4*)(ob + c * GSZ * GSZ))[t]);

    // 2) scan: all 8192 batch points, 12 float4 loads issued up front
    const float* xb = x + (size_t)b * 6 * NPT;
    const int n0 = 4 * t, n1 = 4 * t + 4096;
    const float4 A0 = *(const float4*)(xb + n0);
    const float4 A1 = *(const float4*)(xb + NPT + n0);
    const float4 A2 = *(const float4*)(xb + 2 * NPT + n0);
    const float4 B0 = *(const float4*)(xb + n1);
    const float4 B1 = *(const float4*)(xb + NPT + n1);
    const float4 B2 = *(const float4*)(xb + 2 * NPT + n1);

    int pk[8];
    int m0 = 0x7fffffff, m1 = 0x7fffffff;
    {
        const float* f0 = (const float*)&A0;
        const float* f1 = (const float*)&A1;
        const float* f2 = (const float*)&A2;
#pragma unroll
        for (int e = 0; e < 4; ++e) {
            int u0, u1;
            compute_pt(f0[e], f1[e], f2[e], u0, u1);
            m0 = min(m0, u0); m1 = min(m1, u1);
            pk[e] = (u0 & 0xffff) | (u1 << 16);
        }
    }
    {
        const float* f0 = (const float*)&B0;
        const float* f1 = (const float*)&B1;
        const float* f2 = (const float*)&B2;
#pragma unroll
        for (int e = 0; e < 4; ++e) {
            int u0, u1;
            compute_pt(f0[e], f1[e], f2[e], u0, u1);
            m0 = min(m0, u0); m1 = min(m1, u1);
            pk[4 + e] = (u0 & 0xffff) | (u1 << 16);
        }
    }
    for (int o = 32; o; o >>= 1) {
        m0 = min(m0, __shfl_down(m0, o));
        m1 = min(m1, __shfl_down(m1, o));
    }
    __shared__ int red0[16], red1[16], osh[2];
    if ((t & 63) == 0) { red0[t >> 6] = m0; red1[t >> 6] = m1; }
    __syncthreads();
    if (t == 0) {
        int a0 = red0[0], a1 = red1[0];
#pragma unroll
        for (int i = 1; i < TPB / 64; ++i) { a0 = min(a0, red0[i]); a1 = min(a1, red1[i]); }
        osh[0] = a0; osh[1] = a1;
    }
    __syncthreads();   // also: vmcnt(0) drain -> stripe zeros acked before atomics
    const int off0 = osh[0], off1 = osh[1];

    // 3) scatter own-stripe survivors via global atomics (~3 per block)
#pragma unroll
    for (int k = 0; k < 8; ++k) {
        int p = pk[k];
        int u0 = (int)(short)(p & 0xffff);
        int u1 = p >> 16;
        int i = u0 - off0, j = u1 - off1;   // >= 0 always
        int il = i - rlo;
        if ((unsigned)il < ROWS && (unsigned)j < GSZ) {
            int n = 4 * t + (k >> 2) * 4096 + (k & 3);
            float* o = ob + (size_t)il * GSZ + j;
            atomicAdd(o + 0 * GSZ * GSZ, xb[3 * NPT + n]);
            atomicAdd(o + 1 * GSZ * GSZ, xb[4 * NPT + n]);
            atomicAdd(o + 2 * GSZ * GSZ, xb[5 * NPT + n]);
        }
    }
}

extern "C" void kernel_launch(void* const* d_in, const int* in_sizes, int n_in,
                              void* d_out, int out_size, void* d_ws, size_t ws_size,
                              hipStream_t stream) {
    const float* x = (const float*)d_in[0];
    float* out = (float*)d_out;
    kone<<<NBLK, TPB, 0, stream>>>(x, out);
}